// Round 1
// baseline (163.066 us; speedup 1.0000x reference)
//
#include <hip/hip_runtime.h>

#define LOG2E 1.4426950408889634f
#define BN_EPS 1e-5f

__device__ __forceinline__ float sigf(float x){
    return __builtin_amdgcn_rcpf(1.f + __builtin_amdgcn_exp2f(-LOG2E * x));
}
__device__ __forceinline__ float tanh_(float x){
    // tanh(x) = 1 - 2/(e^{2x}+1); saturates correctly for large |x|
    return 1.f - 2.f * __builtin_amdgcn_rcpf(__builtin_amdgcn_exp2f((2.f*LOG2E) * x) + 1.f);
}
__device__ __forceinline__ float relu_(float x){ return fmaxf(x, 0.f); }

__device__ __forceinline__ float wsum(float v){
    #pragma unroll
    for (int m = 32; m >= 1; m >>= 1) v += __shfl_xor(v, m, 64);
    return v;
}

// compute z1[18] = W1 @ [emb[idx], feats] + b1 for one row
__device__ __forceinline__ void z1_row(const float* __restrict__ x, const float* __restrict__ emb,
                                       const float* __restrict__ W1, const float* __restrict__ b1,
                                       long row, float z1[18])
{
    const float4* xv = (const float4*)(x + row * 8);
    float4 p = xv[0];
    float4 q = xv[1];
    int idx = (int)p.x;
    float2 e = ((const float2*)emb)[idx];
    float h0[9];
    h0[0] = e.x; h0[1] = e.y;
    h0[2] = p.y; h0[3] = p.z; h0[4] = p.w;
    h0[5] = q.x; h0[6] = q.y; h0[7] = q.z; h0[8] = q.w;
    #pragma unroll
    for (int k = 0; k < 18; ++k){
        float s = b1[k];
        #pragma unroll
        for (int j = 0; j < 9; ++j) s = fmaf(W1[k*9 + j], h0[j], s);
        z1[k] = s;
    }
}

// ---------------- Kernel 1: stats of z1 (18 ch) ----------------
__global__ __launch_bounds__(256) void k_stats1(const float* __restrict__ x, const float* __restrict__ emb,
                                                const float* __restrict__ W1, const float* __restrict__ b1,
                                                float* __restrict__ stats, int B)
{
    float as[18], aq[18];
    #pragma unroll
    for (int k = 0; k < 18; ++k){ as[k] = 0.f; aq[k] = 0.f; }
    long base = (long)blockIdx.x * 1024 + threadIdx.x;
    #pragma unroll
    for (int r = 0; r < 4; ++r){
        long row = base + r * 256;
        if (row < B){
            float z1[18];
            z1_row(x, emb, W1, b1, row, z1);
            #pragma unroll
            for (int k = 0; k < 18; ++k){ as[k] += z1[k]; aq[k] = fmaf(z1[k], z1[k], aq[k]); }
        }
    }
    __shared__ float sm[36];
    if (threadIdx.x < 36) sm[threadIdx.x] = 0.f;
    __syncthreads();
    bool l0 = (threadIdx.x & 63) == 0;
    #pragma unroll
    for (int k = 0; k < 18; ++k){
        float s = wsum(as[k]);
        float q = wsum(aq[k]);
        if (l0){ atomicAdd(&sm[k], s); atomicAdd(&sm[18 + k], q); }
    }
    __syncthreads();
    if (threadIdx.x < 36) atomicAdd(&stats[threadIdx.x], sm[threadIdx.x]);
}

// ---------------- Kernel 2: stats of z2 (9 ch) ----------------
__global__ __launch_bounds__(256) void k_stats2(const float* __restrict__ x, const float* __restrict__ emb,
                                                const float* __restrict__ W1, const float* __restrict__ b1,
                                                const float* __restrict__ g1, const float* __restrict__ be1,
                                                const float* __restrict__ W2, const float* __restrict__ b2,
                                                float* __restrict__ stats, int B)
{
    float invB = 1.f / (float)B;
    float sc[18], sh[18];
    #pragma unroll
    for (int k = 0; k < 18; ++k){
        float mu  = stats[k] * invB;
        float var = fmaf(-mu, mu, stats[18 + k] * invB);
        float rs  = __builtin_amdgcn_rsqf(var + BN_EPS);
        sc[k] = g1[k] * rs;
        sh[k] = fmaf(-mu, sc[k], be1[k]);
    }
    float as[9], aq[9];
    #pragma unroll
    for (int k = 0; k < 9; ++k){ as[k] = 0.f; aq[k] = 0.f; }
    long base = (long)blockIdx.x * 1024 + threadIdx.x;
    #pragma unroll
    for (int r = 0; r < 4; ++r){
        long row = base + r * 256;
        if (row < B){
            float z1[18];
            z1_row(x, emb, W1, b1, row, z1);
            float a1[18];
            #pragma unroll
            for (int k = 0; k < 18; ++k) a1[k] = relu_(fmaf(sc[k], z1[k], sh[k]));
            #pragma unroll
            for (int k = 0; k < 9; ++k){
                float s = b2[k];
                #pragma unroll
                for (int j = 0; j < 18; ++j) s = fmaf(W2[k*18 + j], a1[j], s);
                as[k] += s; aq[k] = fmaf(s, s, aq[k]);
            }
        }
    }
    __shared__ float sm[18];
    if (threadIdx.x < 18) sm[threadIdx.x] = 0.f;
    __syncthreads();
    bool l0 = (threadIdx.x & 63) == 0;
    #pragma unroll
    for (int k = 0; k < 9; ++k){
        float s = wsum(as[k]);
        float q = wsum(aq[k]);
        if (l0){ atomicAdd(&sm[k], s); atomicAdd(&sm[9 + k], q); }
    }
    __syncthreads();
    if (threadIdx.x < 18) atomicAdd(&stats[36 + threadIdx.x], sm[threadIdx.x]);
}

// ---------------- LSTM helpers ----------------
template<bool REV>
__device__ __forceinline__ void lstm1(const float* __restrict__ W, const float* __restrict__ U,
                                      const float* __restrict__ bb, const float xin[9], float out[9][2])
{
    float h[2] = {0.f, 0.f}, c[2] = {0.f, 0.f};
    #pragma unroll
    for (int s = 0; s < 9; ++s){
        const int t = REV ? 8 - s : s;
        float xt = xin[t];
        float z[8];
        #pragma unroll
        for (int r = 0; r < 8; ++r)
            z[r] = fmaf(W[r], xt, fmaf(U[2*r], h[0], fmaf(U[2*r + 1], h[1], bb[r])));
        #pragma unroll
        for (int k = 0; k < 2; ++k){
            float ig = sigf(z[k]);
            float fg = sigf(z[2 + k]);
            float gg = tanh_(z[4 + k]);
            float og = sigf(z[6 + k]);
            c[k] = fmaf(fg, c[k], ig * gg);
            h[k] = og * tanh_(c[k]);
        }
        out[t][0] = h[0]; out[t][1] = h[1];
    }
}

template<bool REV>
__device__ __forceinline__ void lstm2(const float* __restrict__ W, const float* __restrict__ U,
                                      const float* __restrict__ bb, const float uin[9][4], float out[9])
{
    float h = 0.f, c = 0.f;
    #pragma unroll
    for (int s = 0; s < 9; ++s){
        const int t = REV ? 8 - s : s;
        float z[4];
        #pragma unroll
        for (int r = 0; r < 4; ++r){
            float acc = fmaf(U[r], h, bb[r]);
            #pragma unroll
            for (int j = 0; j < 4; ++j) acc = fmaf(W[4*r + j], uin[t][j], acc);
            z[r] = acc;
        }
        float ig = sigf(z[0]);
        float fg = sigf(z[1]);
        float gg = tanh_(z[2]);
        float og = sigf(z[3]);
        c = fmaf(fg, c, ig * gg);
        h = og * tanh_(c);
        out[t] = h;
    }
}

// ---------------- Kernel 3: full chain + output ----------------
__global__ __launch_bounds__(256) void k_main(const float* __restrict__ x, const float* __restrict__ emb,
    const float* __restrict__ W1, const float* __restrict__ b1,
    const float* __restrict__ g1, const float* __restrict__ be1,
    const float* __restrict__ W2, const float* __restrict__ b2,
    const float* __restrict__ g2, const float* __restrict__ be2,
    const float* __restrict__ w1f, const float* __restrict__ u1f, const float* __restrict__ c1f,
    const float* __restrict__ w1r, const float* __restrict__ u1r, const float* __restrict__ c1r,
    const float* __restrict__ w2f, const float* __restrict__ u2f, const float* __restrict__ c2f,
    const float* __restrict__ w2r, const float* __restrict__ u2r, const float* __restrict__ c2r,
    const float* __restrict__ stats, float* __restrict__ out, int B)
{
    long row = (long)blockIdx.x * 256 + threadIdx.x;
    if (row >= B) return;
    float invB = 1.f / (float)B;

    float z1[18];
    z1_row(x, emb, W1, b1, row, z1);
    float a1[18];
    #pragma unroll
    for (int k = 0; k < 18; ++k){
        float mu  = stats[k] * invB;
        float var = fmaf(-mu, mu, stats[18 + k] * invB);
        float rs  = __builtin_amdgcn_rsqf(var + BN_EPS);
        a1[k] = relu_(fmaf(g1[k] * rs, z1[k] - mu, be1[k]));
    }
    float a2[9];
    #pragma unroll
    for (int k = 0; k < 9; ++k){
        float s = b2[k];
        #pragma unroll
        for (int j = 0; j < 18; ++j) s = fmaf(W2[k*18 + j], a1[j], s);
        float mu  = stats[36 + k] * invB;
        float var = fmaf(-mu, mu, stats[45 + k] * invB);
        float rs  = __builtin_amdgcn_rsqf(var + BN_EPS);
        a2[k] = relu_(fmaf(g2[k] * rs, s - mu, be2[k]));
    }

    float hf[9][2], hr[9][2];
    lstm1<false>(w1f, u1f, c1f, a2, hf);
    lstm1<true >(w1r, u1r, c1r, a2, hr);

    float u[9][4];
    #pragma unroll
    for (int t = 0; t < 9; ++t){
        u[t][0] = relu_(hf[t][0]);
        u[t][1] = relu_(hf[t][1]);
        u[t][2] = relu_(hr[t][0]);
        u[t][3] = relu_(hr[t][1]);
    }

    float of[9], orr[9];
    lstm2<false>(w2f, u2f, c2f, u, of);
    lstm2<true >(w2r, u2r, c2r, u, orr);

    float2* op = (float2*)(out + row * 18);
    #pragma unroll
    for (int t = 0; t < 9; ++t) op[t] = make_float2(of[t], orr[t]);
}

extern "C" void kernel_launch(void* const* d_in, const int* in_sizes, int n_in,
                              void* d_out, int out_size, void* d_ws, size_t ws_size,
                              hipStream_t stream)
{
    const float* x    = (const float*)d_in[0];
    const float* emb  = (const float*)d_in[1];
    const float* W1   = (const float*)d_in[2];
    const float* b1   = (const float*)d_in[3];
    const float* g1   = (const float*)d_in[4];
    const float* be1  = (const float*)d_in[5];
    const float* W2   = (const float*)d_in[6];
    const float* b2   = (const float*)d_in[7];
    const float* g2   = (const float*)d_in[8];
    const float* be2  = (const float*)d_in[9];
    const float* l1Wf = (const float*)d_in[10];
    const float* l1Uf = (const float*)d_in[11];
    const float* l1bf = (const float*)d_in[12];
    const float* l1Wr = (const float*)d_in[13];
    const float* l1Ur = (const float*)d_in[14];
    const float* l1br = (const float*)d_in[15];
    const float* l2Wf = (const float*)d_in[16];
    const float* l2Uf = (const float*)d_in[17];
    const float* l2bf = (const float*)d_in[18];
    const float* l2Wr = (const float*)d_in[19];
    const float* l2Ur = (const float*)d_in[20];
    const float* l2br = (const float*)d_in[21];

    int B = in_sizes[0] / 8;
    float* stats = (float*)d_ws;

    // stats layout: [0:18] sum1, [18:36] sumsq1, [36:45] sum2, [45:54] sumsq2
    hipMemsetAsync(d_ws, 0, 64 * sizeof(float), stream);

    int nb12 = (B + 1023) / 1024;   // 4 rows/thread, 256 threads
    int nb3  = (B + 255) / 256;     // 1 row/thread

    k_stats1<<<nb12, 256, 0, stream>>>(x, emb, W1, b1, stats, B);
    k_stats2<<<nb12, 256, 0, stream>>>(x, emb, W1, b1, g1, be1, W2, b2, stats, B);
    k_main<<<nb3, 256, 0, stream>>>(x, emb, W1, b1, g1, be1, W2, b2, g2, be2,
                                    l1Wf, l1Uf, l1bf, l1Wr, l1Ur, l1br,
                                    l2Wf, l2Uf, l2bf, l2Wr, l2Ur, l2br,
                                    stats, (float*)d_out, B);
}

// Round 2
// 152.821 us; speedup vs baseline: 1.0670x; 1.0670x over previous
//
#include <hip/hip_runtime.h>

#define LOG2E 1.4426950408889634f
#define BN_EPS 1e-5f

typedef float f32x2 __attribute__((ext_vector_type(2)));
typedef float f32x4 __attribute__((ext_vector_type(4)));

__device__ __forceinline__ float sigf(float x){
    return __builtin_amdgcn_rcpf(1.f + __builtin_amdgcn_exp2f(-LOG2E * x));
}
// sig(a)*tanh(b) with a single rcp: A=e^a, B=e^{2b} -> A(B-1)/((1+A)(B+1))
__device__ __forceinline__ float sigtanh(float a, float b){
    float A  = __builtin_amdgcn_exp2f(LOG2E * a);
    float Bv = __builtin_amdgcn_exp2f((2.f * LOG2E) * b);
    float num = A * (Bv - 1.f);
    float den = (1.f + A) * (1.f + Bv);
    return num * __builtin_amdgcn_rcpf(den);
}
__device__ __forceinline__ float relu_(float x){ return fmaxf(x, 0.f); }

__device__ __forceinline__ float wsum(float v){
    #pragma unroll
    for (int m = 32; m >= 1; m >>= 1) v += __shfl_xor(v, m, 64);
    return v;
}

__device__ constexpr int TRI(int j, int l){ return j*9 - j*(j-1)/2 + (l - j); } // j<=l, 45 entries

__device__ __forceinline__ void load_h0(const float* __restrict__ x, const float* __restrict__ emb,
                                        long row, float h0[9])
{
    const float4* xv = (const float4*)(x + row * 8);
    float4 p = xv[0];
    float4 q = xv[1];
    int idx = (int)p.x;
    float2 e = ((const float2*)emb)[idx];
    h0[0] = e.x; h0[1] = e.y;
    h0[2] = p.y; h0[3] = p.z; h0[4] = p.w;
    h0[5] = q.x; h0[6] = q.y; h0[7] = q.z; h0[8] = q.w;
}

// ---------------- Kernel 1: moments of h0 (9 sums + 45 second moments) ----------------
__global__ __launch_bounds__(256) void k_moments(const float* __restrict__ x, const float* __restrict__ emb,
                                                 float* __restrict__ stats, int B)
{
    float s9[9], mt[45];
    #pragma unroll
    for (int j = 0; j < 9; ++j) s9[j] = 0.f;
    #pragma unroll
    for (int t = 0; t < 45; ++t) mt[t] = 0.f;

    long base = (long)blockIdx.x * 1024 + threadIdx.x;
    #pragma unroll
    for (int r = 0; r < 4; ++r){
        long row = base + r * 256;
        if (row < B){
            float h0[9];
            load_h0(x, emb, row, h0);
            #pragma unroll
            for (int j = 0; j < 9; ++j){
                s9[j] += h0[j];
                #pragma unroll
                for (int l = j; l < 9; ++l)
                    mt[TRI(j,l)] = fmaf(h0[j], h0[l], mt[TRI(j,l)]);
            }
        }
    }
    __shared__ float sm[54];
    if (threadIdx.x < 54) sm[threadIdx.x] = 0.f;
    __syncthreads();
    bool l0 = (threadIdx.x & 63) == 0;
    #pragma unroll
    for (int j = 0; j < 9; ++j){
        float v = wsum(s9[j]);
        if (l0) atomicAdd(&sm[j], v);
    }
    #pragma unroll
    for (int t = 0; t < 45; ++t){
        float v = wsum(mt[t]);
        if (l0) atomicAdd(&sm[9 + t], v);
    }
    __syncthreads();
    if (threadIdx.x < 9)  atomicAdd(&stats[threadIdx.x], sm[threadIdx.x]);
    else if (threadIdx.x < 54) atomicAdd(&stats[16 + threadIdx.x - 9], sm[threadIdx.x]);
}

// BN1 scale/shift from moments; threads 0..17 -> LDS
__device__ __forceinline__ void bn1_from_moments(const float* __restrict__ stats,
                                                 const float* __restrict__ W1, const float* __restrict__ b1,
                                                 const float* __restrict__ g1, const float* __restrict__ be1,
                                                 float invB, float* smem_sc, float* smem_sh)
{
    if (threadIdx.x < 18){
        int k = threadIdx.x;
        float w[9];
        #pragma unroll
        for (int j = 0; j < 9; ++j) w[j] = W1[k*9 + j];
        float dot9 = 0.f, q = 0.f;
        #pragma unroll
        for (int j = 0; j < 9; ++j){
            dot9 = fmaf(w[j], stats[j], dot9);
            q = fmaf(w[j]*w[j], stats[16 + TRI(j,j)], q);
            #pragma unroll
            for (int l = j+1; l < 9; ++l)
                q = fmaf(2.f*w[j]*w[l], stats[16 + TRI(j,l)], q);
        }
        float m1  = dot9 * invB;
        float var = fmaf(-m1, m1, q * invB);
        float mu  = m1 + b1[k];
        float sc  = g1[k] * __builtin_amdgcn_rsqf(var + BN_EPS);
        smem_sc[k] = sc;
        smem_sh[k] = fmaf(-mu, sc, be1[k]);
    }
    __syncthreads();
}

// ---------------- Kernel 2: z2 stats (+ optional z2 cache) ----------------
template<int STORE_Z2>
__global__ __launch_bounds__(256) void k_stats2(const float* __restrict__ x, const float* __restrict__ emb,
                                                const float* __restrict__ W1, const float* __restrict__ b1,
                                                const float* __restrict__ g1, const float* __restrict__ be1,
                                                const float* __restrict__ W2, const float* __restrict__ b2,
                                                float* __restrict__ stats, float* __restrict__ z2buf, int B)
{
    __shared__ float s_sc[18], s_sh[18];
    bn1_from_moments(stats, W1, b1, g1, be1, 1.f/(float)B, s_sc, s_sh);

    float sc1[18], sh1[18];
    #pragma unroll
    for (int k = 0; k < 18; ++k){ sc1[k] = s_sc[k]; sh1[k] = s_sh[k]; }

    float as[9], aq[9];
    #pragma unroll
    for (int k = 0; k < 9; ++k){ as[k] = 0.f; aq[k] = 0.f; }

    long base = (long)blockIdx.x * 1024 + threadIdx.x;
    #pragma unroll
    for (int r = 0; r < 4; ++r){
        long row = base + r * 256;
        if (row < B){
            float h0[9];
            load_h0(x, emb, row, h0);
            float a1[18];
            #pragma unroll
            for (int k = 0; k < 18; ++k){
                float s = b1[k];
                #pragma unroll
                for (int j = 0; j < 9; ++j) s = fmaf(W1[k*9 + j], h0[j], s);
                a1[k] = relu_(fmaf(sc1[k], s, sh1[k]));
            }
            #pragma unroll
            for (int k = 0; k < 9; ++k){
                float s = b2[k];
                #pragma unroll
                for (int j = 0; j < 18; ++j) s = fmaf(W2[k*18 + j], a1[j], s);
                as[k] += s; aq[k] = fmaf(s, s, aq[k]);
                if (STORE_Z2) z2buf[(long)k * B + row] = s;
            }
        }
    }
    __shared__ float sm[18];
    if (threadIdx.x < 18) sm[threadIdx.x] = 0.f;
    __syncthreads();
    bool l0 = (threadIdx.x & 63) == 0;
    #pragma unroll
    for (int k = 0; k < 9; ++k){
        float s = wsum(as[k]);
        float q = wsum(aq[k]);
        if (l0){ atomicAdd(&sm[k], s); atomicAdd(&sm[9 + k], q); }
    }
    __syncthreads();
    if (threadIdx.x < 9)       atomicAdd(&stats[64 + threadIdx.x], sm[threadIdx.x]);
    else if (threadIdx.x < 18) atomicAdd(&stats[80 + threadIdx.x - 9], sm[threadIdx.x]);
}

__device__ __forceinline__ f32x2 mk2(float a, float b){ f32x2 r; r.x=a; r.y=b; return r; }
__device__ __forceinline__ f32x4 mk4(float a, float b, float c, float d){ f32x4 r; r.x=a; r.y=b; r.z=c; r.w=d; return r; }

// ---------------- Kernel 3: BN2 + biLSTM x2 + output ----------------
template<int USE_WS>
__global__ __launch_bounds__(256) void k_main(const float* __restrict__ x, const float* __restrict__ emb,
    const float* __restrict__ W1, const float* __restrict__ b1,
    const float* __restrict__ g1, const float* __restrict__ be1,
    const float* __restrict__ W2, const float* __restrict__ b2,
    const float* __restrict__ g2, const float* __restrict__ be2,
    const float* __restrict__ w1f, const float* __restrict__ u1f, const float* __restrict__ c1f,
    const float* __restrict__ w1r, const float* __restrict__ u1r, const float* __restrict__ c1r,
    const float* __restrict__ w2f, const float* __restrict__ u2f, const float* __restrict__ c2f,
    const float* __restrict__ w2r, const float* __restrict__ u2r, const float* __restrict__ c2r,
    const float* __restrict__ stats, const float* __restrict__ z2buf,
    float* __restrict__ out, int B)
{
    __shared__ float s_sc[18], s_sh[18];
    float invB = 1.f / (float)B;
    if (!USE_WS) bn1_from_moments(stats, W1, b1, g1, be1, invB, s_sc, s_sh);

    long row = (long)blockIdx.x * 256 + threadIdx.x;
    if (row >= B) return;

    // ---- a2 = relu(BN2(z2)) ----
    float a2[9];
    #pragma unroll
    for (int k = 0; k < 9; ++k){
        float zc;
        if (USE_WS){
            zc = z2buf[(long)k * B + row];
        } else {
            zc = 0.f; // computed below
        }
        a2[k] = zc;
    }
    if (!USE_WS){
        float h0[9];
        load_h0(x, emb, row, h0);
        float a1[18];
        #pragma unroll
        for (int k = 0; k < 18; ++k){
            float s = b1[k];
            #pragma unroll
            for (int j = 0; j < 9; ++j) s = fmaf(W1[k*9 + j], h0[j], s);
            a1[k] = relu_(fmaf(s_sc[k], s, s_sh[k]));
        }
        #pragma unroll
        for (int k = 0; k < 9; ++k){
            float s = b2[k];
            #pragma unroll
            for (int j = 0; j < 18; ++j) s = fmaf(W2[k*18 + j], a1[j], s);
            a2[k] = s;
        }
    }
    #pragma unroll
    for (int k = 0; k < 9; ++k){
        float mu  = stats[64 + k] * invB;
        float var = fmaf(-mu, mu, stats[80 + k] * invB);
        float sc  = g2[k] * __builtin_amdgcn_rsqf(var + BN_EPS);
        a2[k] = relu_(fmaf(sc, a2[k] - mu, be2[k]));
    }

    // ---- biLSTM layer 1, packed [fwd0, fwd1, rev0, rev1] ----
    f32x4 W4[4], U04[4], U14[4], B4[4];
    #pragma unroll
    for (int g = 0; g < 4; ++g){
        W4[g]  = mk4(w1f[2*g], w1f[2*g+1], w1r[2*g], w1r[2*g+1]);
        U04[g] = mk4(u1f[(2*g)*2], u1f[(2*g+1)*2], u1r[(2*g)*2], u1r[(2*g+1)*2]);
        U14[g] = mk4(u1f[(2*g)*2+1], u1f[(2*g+1)*2+1], u1r[(2*g)*2+1], u1r[(2*g+1)*2+1]);
        B4[g]  = mk4(c1f[2*g], c1f[2*g+1], c1r[2*g], c1r[2*g+1]);
    }
    f32x4 h4 = {0.f, 0.f, 0.f, 0.f};
    f32x4 c4 = {0.f, 0.f, 0.f, 0.f};
    float u_[9][4];
    #pragma unroll
    for (int s = 0; s < 9; ++s){
        const int tf = s, tr = 8 - s;
        f32x4 xt4 = mk4(a2[tf], a2[tf], a2[tr], a2[tr]);
        f32x4 hx  = mk4(h4.x, h4.x, h4.z, h4.z);
        f32x4 hy  = mk4(h4.y, h4.y, h4.w, h4.w);
        f32x4 z[4];
        #pragma unroll
        for (int g = 0; g < 4; ++g)
            z[g] = __builtin_elementwise_fma(W4[g], xt4,
                    __builtin_elementwise_fma(U04[g], hx,
                     __builtin_elementwise_fma(U14[g], hy, B4[g])));
        f32x4 icg, fs;
        #pragma unroll
        for (int c = 0; c < 4; ++c){
            icg[c] = sigtanh(z[0][c], z[2][c]);
            fs[c]  = sigf(z[1][c]);
        }
        c4 = __builtin_elementwise_fma(fs, c4, icg);
        #pragma unroll
        for (int c = 0; c < 4; ++c) h4[c] = sigtanh(z[3][c], c4[c]);
        u_[tf][0] = relu_(h4.x);
        u_[tf][1] = relu_(h4.y);
        u_[tr][2] = relu_(h4.z);
        u_[tr][3] = relu_(h4.w);
    }

    // ---- biLSTM layer 2, packed [fwd, rev] ----
    f32x2 w2v[4][4], u2v[4], b2v[4];
    #pragma unroll
    for (int r = 0; r < 4; ++r){
        #pragma unroll
        for (int j = 0; j < 4; ++j) w2v[r][j] = mk2(w2f[4*r + j], w2r[4*r + j]);
        u2v[r] = mk2(u2f[r], u2r[r]);
        b2v[r] = mk2(c2f[r], c2r[r]);
    }
    f32x2 h2 = {0.f, 0.f};
    f32x2 cc = {0.f, 0.f};
    long obase = row * 18;
    #pragma unroll
    for (int s = 0; s < 9; ++s){
        const int tf = s, tr = 8 - s;
        f32x2 z[4];
        #pragma unroll
        for (int r = 0; r < 4; ++r){
            f32x2 acc = __builtin_elementwise_fma(u2v[r], h2, b2v[r]);
            #pragma unroll
            for (int j = 0; j < 4; ++j)
                acc = __builtin_elementwise_fma(w2v[r][j], mk2(u_[tf][j], u_[tr][j]), acc);
            z[r] = acc;
        }
        f32x2 icg, fs;
        #pragma unroll
        for (int c = 0; c < 2; ++c){
            icg[c] = sigtanh(z[0][c], z[2][c]);
            fs[c]  = sigf(z[1][c]);
        }
        cc = __builtin_elementwise_fma(fs, cc, icg);
        float hfo = sigtanh(z[3][0], cc.x);
        float hro = sigtanh(z[3][1], cc.y);
        h2 = mk2(hfo, hro);
        out[obase + 2*tf]     = hfo;
        out[obase + 2*tr + 1] = hro;
    }
}

extern "C" void kernel_launch(void* const* d_in, const int* in_sizes, int n_in,
                              void* d_out, int out_size, void* d_ws, size_t ws_size,
                              hipStream_t stream)
{
    const float* x    = (const float*)d_in[0];
    const float* emb  = (const float*)d_in[1];
    const float* W1   = (const float*)d_in[2];
    const float* b1   = (const float*)d_in[3];
    const float* g1   = (const float*)d_in[4];
    const float* be1  = (const float*)d_in[5];
    const float* W2   = (const float*)d_in[6];
    const float* b2   = (const float*)d_in[7];
    const float* g2   = (const float*)d_in[8];
    const float* be2  = (const float*)d_in[9];
    const float* l1Wf = (const float*)d_in[10];
    const float* l1Uf = (const float*)d_in[11];
    const float* l1bf = (const float*)d_in[12];
    const float* l1Wr = (const float*)d_in[13];
    const float* l1Ur = (const float*)d_in[14];
    const float* l1br = (const float*)d_in[15];
    const float* l2Wf = (const float*)d_in[16];
    const float* l2Uf = (const float*)d_in[17];
    const float* l2bf = (const float*)d_in[18];
    const float* l2Wr = (const float*)d_in[19];
    const float* l2Ur = (const float*)d_in[20];
    const float* l2br = (const float*)d_in[21];

    int B = in_sizes[0] / 8;
    float* stats = (float*)d_ws;
    float* z2buf = (float*)d_ws + 1024;
    size_t need = (1024 + (size_t)9 * B) * sizeof(float);
    bool use_ws = ws_size >= need;

    // stats layout: [0:9] sum h0, [16:61] upper-tri second moments,
    //               [64:73] sum z2, [80:89] sumsq z2
    hipMemsetAsync(d_ws, 0, 128 * sizeof(float), stream);

    int nb12 = (B + 1023) / 1024;
    int nb3  = (B + 255) / 256;

    k_moments<<<nb12, 256, 0, stream>>>(x, emb, stats, B);
    if (use_ws){
        k_stats2<1><<<nb12, 256, 0, stream>>>(x, emb, W1, b1, g1, be1, W2, b2, stats, z2buf, B);
        k_main<1><<<nb3, 256, 0, stream>>>(x, emb, W1, b1, g1, be1, W2, b2, g2, be2,
                                           l1Wf, l1Uf, l1bf, l1Wr, l1Ur, l1br,
                                           l2Wf, l2Uf, l2bf, l2Wr, l2Ur, l2br,
                                           stats, z2buf, (float*)d_out, B);
    } else {
        k_stats2<0><<<nb12, 256, 0, stream>>>(x, emb, W1, b1, g1, be1, W2, b2, stats, z2buf, B);
        k_main<0><<<nb3, 256, 0, stream>>>(x, emb, W1, b1, g1, be1, W2, b2, g2, be2,
                                           l1Wf, l1Uf, l1bf, l1Wr, l1Ur, l1br,
                                           l2Wf, l2Uf, l2bf, l2Wr, l2Ur, l2br,
                                           stats, z2buf, (float*)d_out, B);
    }
}